// Round 1
// baseline (109.561 us; speedup 1.0000x reference)
//
#include <hip/hip_runtime.h>
#include <math.h>

#define BB 32
#define Q 2000
#define NC 91
#define NA 18
#define K 100
#define N (Q*NC)          // 182000
#define NBINS 4096
#define CAP 8192

// output offsets (flat f32 concat in reference return order)
#define O_V     0        // (B,K)      3200
#define O_LAB   3200     // (B,K)      3200
#define O_BOX   6400     // (B,K,4)    12800
#define O_VG    19200    // (B,K)      3200
#define O_LABG  22400    // (B,K)      3200
#define O_BG    25600    // (B,K,5)    16000
#define O_ADJ   41600    // (B,K,K)    320000
#define O_KEEP  361600   // (B,K)      3200

__device__ __forceinline__ unsigned okey(float f) {
    unsigned u = __float_as_uint(f);
    return (u & 0x80000000u) ? ~u : (u | 0x80000000u);
}

__device__ __forceinline__ float sigm(float x) { return 1.f / (1.f + expf(-x)); }

// One block per (batch, which-branch). Exact top-K (desc value, asc index tie-break)
// via 4096-bin histogram select + candidate collection + O(c^2) ranking.
__global__ __launch_bounds__(1024) void topk_kernel(const float* __restrict__ logits,
                                                    const float* __restrict__ logits_g,
                                                    float* __restrict__ out_v,
                                                    int* __restrict__ out_i) {
    const int b = blockIdx.x >> 1;
    const int which = blockIdx.x & 1;
    const float* src = (which ? logits_g : logits) + (size_t)b * N;
    float* ov = out_v + (size_t)(which * BB + b) * K;
    int*   oi = out_i + (size_t)(which * BB + b) * K;

    __shared__ unsigned hist[NBINS];
    __shared__ float cv[CAP];
    __shared__ int   ci[CAP];
    __shared__ unsigned s_cnt;
    __shared__ unsigned s_thr;

    const int tid = threadIdx.x;
    const int bs = blockDim.x;

    for (int i = tid; i < NBINS; i += bs) hist[i] = 0u;
    __syncthreads();

    const float4* src4 = (const float4*)src;
    const int N4 = N / 4;   // 45500, N divisible by 4
    for (int i = tid; i < N4; i += bs) {
        float4 v = src4[i];
        atomicAdd(&hist[okey(v.x) >> 20], 1u);
        atomicAdd(&hist[okey(v.y) >> 20], 1u);
        atomicAdd(&hist[okey(v.z) >> 20], 1u);
        atomicAdd(&hist[okey(v.w) >> 20], 1u);
    }
    __syncthreads();

    if (tid == 0) {
        unsigned c = 0; int t = NBINS - 1;
        for (; t > 0; --t) { c += hist[t]; if (c >= (unsigned)K) break; }
        s_thr = (unsigned)t;
        s_cnt = 0u;
    }
    __syncthreads();

    const unsigned thr = s_thr;
    for (int i = tid; i < N4; i += bs) {
        float4 v = src4[i];
        float vs[4] = {v.x, v.y, v.z, v.w};
        #pragma unroll
        for (int u = 0; u < 4; ++u) {
            if ((okey(vs[u]) >> 20) >= thr) {
                unsigned p = atomicAdd(&s_cnt, 1u);
                if (p < CAP) { cv[p] = vs[u]; ci[p] = i * 4 + u; }
            }
        }
    }
    __syncthreads();

    const int c = (int)(s_cnt < (unsigned)CAP ? s_cnt : (unsigned)CAP);
    for (int i = tid; i < c; i += bs) {
        const float vi = cv[i];
        const int ii = ci[i];
        int r = 0;
        for (int j = 0; j < c; ++j) {
            const float vj = cv[j];
            if (vj > vi || (vj == vi && ci[j] < ii)) r++;
        }
        if (r < K) { ov[r] = vi; oi[r] = ii; }
    }
}

// One block per batch, thread k < K handles one selected slot for both branches.
__global__ void finalize_kernel(const float* __restrict__ boxes_in,
                                const float* __restrict__ boxes_g_in,
                                const float* __restrict__ angles_in,
                                const float* __restrict__ tsz,
                                const float* __restrict__ tv,
                                const int* __restrict__ ti,
                                float* __restrict__ out,
                                int* __restrict__ ws_keep,
                                int* __restrict__ ws_q) {
    const int b = blockIdx.x;
    const int k = threadIdx.x;
    if (k >= K) return;
    const float H = tsz[b * 2 + 0];
    const float W = tsz[b * 2 + 1];

    // --- detection branch ---
    const float v = tv[b * K + k];
    const int idx = ti[b * K + k];
    const float s = sigm(v);
    const int keep = (s > 0.3f) ? 1 : 0;
    const int lab = idx % NC;
    const int q = idx / NC;
    out[O_V + b * K + k] = s;
    out[O_LAB + b * K + k] = keep ? (float)lab : -1.f;
    const float* pb = boxes_in + ((size_t)b * Q + q) * 4;
    const float cx = pb[0], cy = pb[1], w = pb[2], h = pb[3];
    float* ob = out + O_BOX + ((size_t)b * K + k) * 4;
    ob[0] = (cx - 0.5f * w) * W;
    ob[1] = (cy - 0.5f * h) * H;
    ob[2] = (cx + 0.5f * w) * W;
    ob[3] = (cy + 0.5f * h) * H;
    out[O_KEEP + b * K + k] = keep ? 1.f : 0.f;
    ws_keep[b * K + k] = keep;
    ws_q[b * K + k] = q;

    // --- grasp branch ---
    const float vg = tv[(BB + b) * K + k];
    const int idxg = ti[(BB + b) * K + k];
    const float sg = sigm(vg);
    const int labg = idxg % NC;
    const int qg = idxg / NC;
    out[O_VG + b * K + k] = sg;
    out[O_LABG + b * K + k] = (float)labg;
    const float* pg = boxes_g_in + ((size_t)b * Q + qg) * 4;
    float* obg = out + O_BG + ((size_t)b * K + k) * 5;
    obg[0] = pg[0] * W;
    obg[1] = pg[1] * H;
    obg[2] = pg[2] * W;
    obg[3] = pg[3] * H;
    const float* pa = angles_in + ((size_t)b * Q + qg) * NA;
    int am = 0;
    float bv = pa[0];
    #pragma unroll
    for (int a = 1; a < NA; ++a) {
        const float x = pa[a];
        if (x > bv) { bv = x; am = a; }   // strict > => first-max, matches argmax
    }
    obg[4] = (float)((am - 8) * 10 - 5);
}

// One block per (b, i); thread j < K computes adj[b, i, j].
__global__ void adj_kernel(const float* __restrict__ adj_in,
                           const int* __restrict__ ws_keep,
                           const int* __restrict__ ws_q,
                           float* __restrict__ out) {
    const int bi = blockIdx.x;         // b*K + i
    const int b = bi / K;
    const int i = bi - b * K;
    const int j = threadIdx.x;
    if (j >= K) return;
    const int qi = ws_q[b * K + i];
    const int ki = ws_keep[b * K + i];
    const int qj = ws_q[b * K + j];
    const int kj = ws_keep[b * K + j];
    float val = 0.f;
    if (ki & kj) {
        const float a = adj_in[((size_t)b * Q + qi) * Q + qj];
        val = sigm(a);
    }
    out[O_ADJ + (size_t)bi * K + j] = val;
}

extern "C" void kernel_launch(void* const* d_in, const int* in_sizes, int n_in,
                              void* d_out, int out_size, void* d_ws, size_t ws_size,
                              hipStream_t stream) {
    const float* pred_logits   = (const float*)d_in[0];
    const float* pred_boxes    = (const float*)d_in[1];
    const float* pred_adj      = (const float*)d_in[2];
    const float* pred_logits_g = (const float*)d_in[3];
    const float* pred_angles_g = (const float*)d_in[4];
    const float* pred_boxes_g  = (const float*)d_in[5];
    const float* tsz           = (const float*)d_in[6];
    float* out = (float*)d_out;

    float* ws_v   = (float*)d_ws;            // 6400 floats (det 0..31, grasp 32..63)
    int*   ws_i   = (int*)(ws_v + 6400);     // 6400 ints
    int*   ws_keep = ws_i + 6400;            // 3200 ints
    int*   ws_q    = ws_keep + 3200;         // 3200 ints

    hipLaunchKernelGGL(topk_kernel, dim3(2 * BB), dim3(1024), 0, stream,
                       pred_logits, pred_logits_g, ws_v, ws_i);
    hipLaunchKernelGGL(finalize_kernel, dim3(BB), dim3(128), 0, stream,
                       pred_boxes, pred_boxes_g, pred_angles_g, tsz,
                       ws_v, ws_i, out, ws_keep, ws_q);
    hipLaunchKernelGGL(adj_kernel, dim3(BB * K), dim3(128), 0, stream,
                       pred_adj, ws_keep, ws_q, out);
}